// Round 4
// baseline (622.926 us; speedup 1.0000x reference)
//
#include <hip/hip_runtime.h>

typedef unsigned short ushort_t;
typedef __attribute__((ext_vector_type(8))) short short8;
typedef __attribute__((ext_vector_type(4))) float f32x4;
typedef __attribute__((ext_vector_type(4))) unsigned short ushort4v;

__device__ inline ushort_t f2bf(float f) {
    union { float f; unsigned u; } v; v.f = f;
    return (ushort_t)((v.u + 0x7FFFu + ((v.u >> 16) & 1u)) >> 16);
}
__device__ inline float bf2f(ushort_t u) {
    union { unsigned u; float f; } v; v.u = ((unsigned)u) << 16;
    return v.f;
}

// async global->LDS, 16B per lane. LDS dest must be wave-uniform-base + lane*16.
__device__ inline void gld16(const ushort_t* g, ushort_t* l) {
    __builtin_amdgcn_global_load_lds(
        (const __attribute__((address_space(1))) unsigned int*)g,
        (__attribute__((address_space(3))) unsigned int*)l, 16, 0, 0);
}

// ---------------------------------------------------------------------------
// Weight transpose + f32->bf16 convert:  w (K x N) f32  ->  out (N x K) bf16
// ---------------------------------------------------------------------------
__global__ void w_transpose_bf16(const float* __restrict__ w, ushort_t* __restrict__ out,
                                 int K, int N) {
    __shared__ float t[64][65];
    const int k0 = blockIdx.y * 64, n0 = blockIdx.x * 64;
    const int tid = threadIdx.x;
#pragma unroll
    for (int i = 0; i < 16; i++) {
        int idx = tid + i * 256;
        int r = idx >> 6, c = idx & 63;
        t[r][c] = w[(size_t)(k0 + r) * N + n0 + c];
    }
    __syncthreads();
#pragma unroll
    for (int i = 0; i < 16; i++) {
        int idx = tid + i * 256;
        int nr = idx >> 6, kc = idx & 63;
        out[(size_t)(n0 + nr) * K + k0 + kc] = f2bf(t[kc][nr]);
    }
}

// ---------------------------------------------------------------------------
// bf16 V (rows x D per head, strided) -> Vt [(b*16+h)*64 + d][Lk]
// ---------------------------------------------------------------------------
__global__ void v_transpose(const ushort_t* __restrict__ V, int vStride, int rowsPerBatch,
                            ushort_t* __restrict__ Vt, int Lk) {
    __shared__ __align__(16) ushort_t t[64][72];
    const int bh = blockIdx.y, k0 = blockIdx.x * 64;
    const int b = bh >> 4, h = bh & 15;
    const int tid = threadIdx.x;
    const ushort_t* src = V + (size_t)(b * rowsPerBatch + k0) * vStride + h * 64;
#pragma unroll
    for (int i = 0; i < 2; i++) {
        int ch = tid + i * 256;
        int r = ch >> 3, c = (ch & 7) * 8;
        *(short8*)(&t[r][c]) = *(const short8*)(src + (size_t)r * vStride + c);
    }
    __syncthreads();
#pragma unroll
    for (int i = 0; i < 2; i++) {
        int ch = tid + i * 256;
        int d = ch >> 3, c = (ch & 7) * 8;
        short8 o;
#pragma unroll
        for (int j = 0; j < 8; j++) o[j] = (short)t[c + j][d];
        *(short8*)(Vt + ((size_t)bh * 64 + d) * Lk + k0 + c) = o;
    }
}

// ---------------------------------------------------------------------------
// Elementwise f32 -> bf16 (vectorized x4)
// ---------------------------------------------------------------------------
__global__ void f32_to_bf16_vec(const float* __restrict__ in, ushort_t* __restrict__ out, int n4) {
    int i = blockIdx.x * blockDim.x + threadIdx.x;
    if (i < n4) {
        float4 v = ((const float4*)in)[i];
        ushort4v o;
        o[0] = f2bf(v.x); o[1] = f2bf(v.y); o[2] = f2bf(v.z); o[3] = f2bf(v.w);
        ((ushort4v*)out)[i] = o;
    }
}

// ---------------------------------------------------------------------------
// LayerNorm over C=1024, f32 in -> bf16 out. One row per block (256 thr).
// ---------------------------------------------------------------------------
__global__ void ln_rows(const float* __restrict__ in, ushort_t* __restrict__ out) {
    __shared__ float s1[4], s2[4];
    const int row = blockIdx.x;
    const int tid = threadIdx.x;
    const float4 v = ((const float4*)(in + (size_t)row * 1024))[tid];
    float s  = v.x + v.y + v.z + v.w;
    float ss = v.x * v.x + v.y * v.y + v.z * v.z + v.w * v.w;
#pragma unroll
    for (int d = 32; d >= 1; d >>= 1) {
        s  += __shfl_down(s, d, 64);
        ss += __shfl_down(ss, d, 64);
    }
    if ((tid & 63) == 0) { s1[tid >> 6] = s; s2[tid >> 6] = ss; }
    __syncthreads();
    float sum = s1[0] + s1[1] + s1[2] + s1[3];
    float sqs = s2[0] + s2[1] + s2[2] + s2[3];
    float mu  = sum * (1.0f / 1024.0f);
    float var = sqs * (1.0f / 1024.0f) - mu * mu;
    float rs  = rsqrtf(var + 1e-6f);
    ushort4v o;
    o[0] = f2bf((v.x - mu) * rs);
    o[1] = f2bf((v.y - mu) * rs);
    o[2] = f2bf((v.z - mu) * rs);
    o[3] = f2bf((v.w - mu) * rs);
    ((ushort4v*)(out + (size_t)row * 1024))[tid] = o;
}

#define EPI_BF16 0
#define EPI_GELU 1
#define EPI_RES  2

// ---------------------------------------------------------------------------
// 128x128 bf16 MFMA GEMM (m97-structure), used for N=1024-class GEMMs.
// ---------------------------------------------------------------------------
template <int EPI>
__global__ void gemm_bt(const ushort_t* __restrict__ A, const ushort_t* __restrict__ Bt,
                        const float* __restrict__ bias, const float* __restrict__ res,
                        void* __restrict__ outp, int M, int N, int K) {
    __shared__ __align__(16) ushort_t As[128 * 64];
    __shared__ __align__(16) ushort_t Bs[128 * 64];
    const int tid = threadIdx.x;
    const int lane = tid & 63, wave = tid >> 6;
    const int m0 = blockIdx.y * 128, n0 = blockIdx.x * 128;
    const int wr = (wave >> 1) * 64, wc = (wave & 1) * 64;
    const int lr = lane & 15, lg = lane >> 4;

    f32x4 acc[4][4];
#pragma unroll
    for (int i = 0; i < 4; i++)
#pragma unroll
        for (int j = 0; j < 4; j++) acc[i][j] = f32x4{0.f, 0.f, 0.f, 0.f};

    for (int k0 = 0; k0 < K; k0 += 64) {
#pragma unroll
        for (int i = 0; i < 4; i++) {
            int ch = tid + i * 256;
            int r = ch >> 3;
            int kcs = (((ch & 7) ^ (r & 7))) * 8;
            gld16(A  + (size_t)(m0 + r) * K + k0 + kcs, As + ch * 8);
            gld16(Bt + (size_t)(n0 + r) * K + k0 + kcs, Bs + ch * 8);
        }
        __syncthreads();
#pragma unroll
        for (int ks = 0; ks < 2; ks++) {
            short8 af[4], bfr[4];
#pragma unroll
            for (int m = 0; m < 4; m++) {
                int r = wr + m * 16 + lr;
                int kc = ks * 4 + lg;
                af[m] = *(const short8*)(As + r * 64 + ((kc ^ (r & 7)) << 3));
            }
#pragma unroll
            for (int n = 0; n < 4; n++) {
                int r = wc + n * 16 + lr;
                int kc = ks * 4 + lg;
                bfr[n] = *(const short8*)(Bs + r * 64 + ((kc ^ (r & 7)) << 3));
            }
#pragma unroll
            for (int m = 0; m < 4; m++)
#pragma unroll
                for (int n = 0; n < 4; n++)
                    acc[m][n] = __builtin_amdgcn_mfma_f32_16x16x32_bf16(af[m], bfr[n], acc[m][n], 0, 0, 0);
        }
        __syncthreads();
    }

#pragma unroll
    for (int m = 0; m < 4; m++) {
        int rowb = m0 + wr + m * 16 + lg * 4;
#pragma unroll
        for (int n = 0; n < 4; n++) {
            int col = n0 + wc + n * 16 + lr;
            float bcol = bias[col];
            f32x4 v = acc[m][n];
#pragma unroll
            for (int q = 0; q < 4; q++) {
                float x = v[q] + bcol;
                if (EPI == EPI_GELU) {
                    float u = 0.7978845608028654f * (x + 0.044715f * x * x * x);
                    x = 0.5f * x * (1.0f + tanhf(u));
                }
                size_t off = (size_t)(rowb + q) * N + col;
                if (EPI == EPI_RES) ((float*)outp)[off] = x + res[off];
                else                ((ushort_t*)outp)[off] = f2bf(x);
            }
        }
    }
}

// ---------------------------------------------------------------------------
// 256x256 8-phase bf16 MFMA GEMM (T3+T4+T5): BK=64, 8 waves (2Mx4N), 128 KB
// double-buffered LDS, counted vmcnt (never 0 mid-loop), raw s_barrier.
// Stage schedule per K-tile t: q0 -> A(t+1) full; q1 -> B-half0(t+2);
// q2 -> B-half1(t+2); q3 -> none; boundary s_waitcnt vmcnt(4).
// Liveness: B-halves of buf(t&1) die after q0's closing barrier; A-halves of
// buf((t+1)&1) died at the previous K-tile boundary barrier.
// ---------------------------------------------------------------------------
template <int EPI>
__global__ __launch_bounds__(512, 2)
void gemm256_bt(const ushort_t* __restrict__ A, const ushort_t* __restrict__ Bt,
                const float* __restrict__ bias,
                void* __restrict__ outp, int M, int N, int K) {
    __shared__ __align__(16) ushort_t As[2][256 * 64];
    __shared__ __align__(16) ushort_t Bs[2][256 * 64];
    const int tid = threadIdx.x;
    const int lane = tid & 63, wave = tid >> 6;
    const int wm = wave >> 2, wn = wave & 3;
    const int lr = lane & 15, lg = lane >> 4;
    const int m0 = blockIdx.y * 256, n0 = blockIdx.x * 256;
    const int nkt = K >> 6;

    f32x4 acc[8][4];
#pragma unroll
    for (int i = 0; i < 8; i++)
#pragma unroll
        for (int j = 0; j < 4; j++) acc[i][j] = f32x4{0.f, 0.f, 0.f, 0.f};

#define STAGE_A(buf, kt)                                                        \
    do {                                                                        \
        _Pragma("unroll")                                                       \
        for (int i_ = 0; i_ < 4; i_++) {                                        \
            int ch_ = tid + i_ * 512;                                           \
            int r_ = ch_ >> 3;                                                  \
            int c_ = (((ch_ & 7) ^ (r_ & 7))) << 3;                             \
            gld16(A + (size_t)(m0 + r_) * K + (kt) + c_, &As[buf][ch_ * 8]);    \
        }                                                                       \
    } while (0)

#define STAGE_BH(buf, kt, half)                                                 \
    do {                                                                        \
        _Pragma("unroll")                                                       \
        for (int i_ = 0; i_ < 2; i_++) {                                        \
            int ch_ = tid + i_ * 512;                                           \
            int r_ = (half) * 128 + (ch_ >> 3);                                 \
            int c_ = (((ch_ & 7) ^ (r_ & 7))) << 3;                             \
            gld16(Bt + (size_t)(n0 + r_) * K + (kt) + c_,                       \
                  &Bs[buf][(half) * 8192 + ch_ * 8]);                           \
        }                                                                       \
    } while (0)

#define RD_A(buf, mf, ks)                                                       \
    (*(const short8*)(&As[buf][(wm * 128 + (mf) * 16 + lr) * 64 +               \
        ((((ks) * 4 + lg) ^ ((wm * 128 + (mf) * 16 + lr) & 7)) << 3)]))
#define RD_B(buf, nf, ks)                                                       \
    (*(const short8*)(&Bs[buf][(wn * 64 + (nf) * 16 + lr) * 64 +                \
        ((((ks) * 4 + lg) ^ ((wn * 64 + (nf) * 16 + lr) & 7)) << 3)]))

#define QUAD(MB)                                                                \
    do {                                                                        \
        _Pragma("unroll")                                                       \
        for (int nf_ = 0; nf_ < 4; nf_++) {                                     \
            acc[MB][nf_]     = __builtin_amdgcn_mfma_f32_16x16x32_bf16(         \
                aq0, bfr[nf_][0], acc[MB][nf_], 0, 0, 0);                       \
            acc[MB][nf_]     = __builtin_amdgcn_mfma_f32_16x16x32_bf16(         \
                aq1, bfr[nf_][1], acc[MB][nf_], 0, 0, 0);                       \
            acc[MB + 1][nf_] = __builtin_amdgcn_mfma_f32_16x16x32_bf16(         \
                aq2, bfr[nf_][0], acc[MB + 1][nf_], 0, 0, 0);                   \
            acc[MB + 1][nf_] = __builtin_amdgcn_mfma_f32_16x16x32_bf16(         \
                aq3, bfr[nf_][1], acc[MB + 1][nf_], 0, 0, 0);                   \
        }                                                                       \
    } while (0)

    // prologue: buf0 full + B(t=1); wait buf0 landed (B(1)'s 4 loads in flight)
    STAGE_A(0, 0);
    STAGE_BH(0, 0, 0); STAGE_BH(0, 0, 1);
    if (nkt > 1) {
        STAGE_BH(1, 64, 0); STAGE_BH(1, 64, 1);
        asm volatile("s_waitcnt vmcnt(4)" ::: "memory");
    } else {
        asm volatile("s_waitcnt vmcnt(0)" ::: "memory");
    }
    __builtin_amdgcn_s_barrier();

    for (int t = 0; t < nkt; ++t) {
        const int b = t & 1;
        short8 bfr[4][2];
#pragma unroll
        for (int nf = 0; nf < 4; nf++) {
            bfr[nf][0] = RD_B(b, nf, 0);
            bfr[nf][1] = RD_B(b, nf, 1);
        }
        // q0: A m{0,1} + full B reads; stage A(t+1)
        {
            short8 aq0 = RD_A(b, 0, 0), aq1 = RD_A(b, 0, 1);
            short8 aq2 = RD_A(b, 1, 0), aq3 = RD_A(b, 1, 1);
            if (t + 1 < nkt) STAGE_A(b ^ 1, (t + 1) << 6);
            __builtin_amdgcn_s_barrier();
            __builtin_amdgcn_s_setprio(1);
            QUAD(0);
            __builtin_amdgcn_s_setprio(0);
            __builtin_amdgcn_s_barrier();
        }
        // q1: A m{2,3}; stage B0(t+2)
        {
            short8 aq0 = RD_A(b, 2, 0), aq1 = RD_A(b, 2, 1);
            short8 aq2 = RD_A(b, 3, 0), aq3 = RD_A(b, 3, 1);
            if (t + 2 < nkt) STAGE_BH(b, (t + 2) << 6, 0);
            __builtin_amdgcn_s_barrier();
            __builtin_amdgcn_s_setprio(1);
            QUAD(2);
            __builtin_amdgcn_s_setprio(0);
            __builtin_amdgcn_s_barrier();
        }
        // q2: A m{4,5}; stage B1(t+2)
        {
            short8 aq0 = RD_A(b, 4, 0), aq1 = RD_A(b, 4, 1);
            short8 aq2 = RD_A(b, 5, 0), aq3 = RD_A(b, 5, 1);
            if (t + 2 < nkt) STAGE_BH(b, (t + 2) << 6, 1);
            __builtin_amdgcn_s_barrier();
            __builtin_amdgcn_s_setprio(1);
            QUAD(4);
            __builtin_amdgcn_s_setprio(0);
            __builtin_amdgcn_s_barrier();
        }
        // q3: A m{6,7}; boundary vmcnt + barrier
        {
            short8 aq0 = RD_A(b, 6, 0), aq1 = RD_A(b, 6, 1);
            short8 aq2 = RD_A(b, 7, 0), aq3 = RD_A(b, 7, 1);
            __builtin_amdgcn_s_barrier();
            __builtin_amdgcn_s_setprio(1);
            QUAD(6);
            __builtin_amdgcn_s_setprio(0);
            if (t + 2 < nkt)      asm volatile("s_waitcnt vmcnt(4)" ::: "memory");
            else if (t + 1 < nkt) asm volatile("s_waitcnt vmcnt(0)" ::: "memory");
            __builtin_amdgcn_s_barrier();
        }
    }

#pragma unroll
    for (int mf = 0; mf < 8; mf++) {
        int rowb = m0 + wm * 128 + mf * 16 + lg * 4;
#pragma unroll
        for (int nf = 0; nf < 4; nf++) {
            int col = n0 + wn * 64 + nf * 16 + lr;
            float bcol = bias[col];
            f32x4 v = acc[mf][nf];
#pragma unroll
            for (int q = 0; q < 4; q++) {
                float x = v[q] + bcol;
                if (EPI == EPI_GELU) {
                    float u = 0.7978845608028654f * (x + 0.044715f * x * x * x);
                    x = 0.5f * x * (1.0f + tanhf(u));
                }
                ((ushort_t*)outp)[(size_t)(rowb + q) * N + col] = f2bf(x);
            }
        }
    }
#undef STAGE_A
#undef STAGE_BH
#undef RD_A
#undef RD_B
#undef QUAD
}

// ---------------------------------------------------------------------------
// Flash attention, bf16 MFMA 16x16x32, D=64. Block = 128 q-rows x 1 head,
// 8 waves (16 q-rows each). Swapped QK^T, packed P, defer-max, double-buffered
// K/V^T staging via global_load_lds, setprio around MFMA clusters.
// ---------------------------------------------------------------------------
__global__ __launch_bounds__(512, 2)
void attn_fwd(const ushort_t* __restrict__ Q, int qStride,
              const ushort_t* __restrict__ Kp, int kvStride, int kvBatchRows,
              const ushort_t* __restrict__ Vt, int Lk,
              ushort_t* __restrict__ O) {
    __shared__ __align__(16) ushort_t Ks[2][64 * 64];
    __shared__ __align__(16) ushort_t Vts[2][64 * 64];
    __shared__ __align__(16) ushort_t Ps[8][16 * 64];
    const int tid = threadIdx.x, lane = tid & 63, wave = tid >> 6;
    const int lr = lane & 15, lg = lane >> 4;
    const int b = blockIdx.z, h = blockIdx.y, qb = blockIdx.x;
    const int qRow0 = b * 2048 + qb * 128;
    const int kvRow0 = b * kvBatchRows;
    const int hc = h * 64;
    const ushort_t* vt_base = Vt + (size_t)(b * 16 + h) * 64 * Lk;

    // Q fragments, pre-scaled by 1/sqrt(64)=0.125 (exact in bf16)
    short8 qf[2];
    {
        const ushort_t* qrow = Q + (size_t)(qRow0 + wave * 16 + lr) * qStride + hc;
        short8 r0 = *(const short8*)(qrow + lg * 8);
        short8 r1 = *(const short8*)(qrow + 32 + lg * 8);
#pragma unroll
        for (int j = 0; j < 8; j++) {
            qf[0][j] = (short)f2bf(bf2f((ushort_t)r0[j]) * 0.125f);
            qf[1][j] = (short)f2bf(bf2f((ushort_t)r1[j]) * 0.125f);
        }
    }

    f32x4 oacc[4];
#pragma unroll
    for (int d = 0; d < 4; d++) oacc[d] = f32x4{0.f, 0.f, 0.f, 0.f};
    float mrun = -INFINITY, lrun = 0.f;

    const int nt = Lk >> 6;

    auto stage = [&](int buf, int kt) {
        int r = tid >> 3;
        int kcs = (((tid & 7) ^ (r & 7))) * 8;
        gld16(Kp + (size_t)(kvRow0 + kt + r) * kvStride + hc + kcs, Ks[buf] + tid * 8);
        gld16(vt_base + (size_t)r * Lk + kt + kcs, Vts[buf] + tid * 8);
    };

    stage(0, 0);
    __syncthreads();
    int cur = 0;

    for (int t = 0; t < nt; ++t) {
        if (t + 1 < nt) stage(cur ^ 1, (t + 1) * 64);

        const ushort_t* Kc = Ks[cur];
        const ushort_t* Vc = Vts[cur];

        // S^T = K Q^T : lane holds S[q=lr][k = n*16 + lg*4 + reg]
        f32x4 sacc[4];
        __builtin_amdgcn_s_setprio(1);
#pragma unroll
        for (int n = 0; n < 4; n++) {
            int r = n * 16 + lr;
            short8 k0 = *(const short8*)(Kc + r * 64 + ((lg ^ (r & 7)) << 3));
            short8 k1 = *(const short8*)(Kc + r * 64 + (((4 + lg) ^ (r & 7)) << 3));
            f32x4 s = f32x4{0.f, 0.f, 0.f, 0.f};
            s = __builtin_amdgcn_mfma_f32_16x16x32_bf16(k0, qf[0], s, 0, 0, 0);
            s = __builtin_amdgcn_mfma_f32_16x16x32_bf16(k1, qf[1], s, 0, 0, 0);
            sacc[n] = s;
        }
        __builtin_amdgcn_s_setprio(0);

        // row max: 15 in-reg fmax + 2 cross-lane
        float mx = sacc[0][0];
#pragma unroll
        for (int n = 0; n < 4; n++)
#pragma unroll
            for (int r = 0; r < 4; r++) if (n | r) mx = fmaxf(mx, sacc[n][r]);
        mx = fmaxf(mx, __shfl_xor(mx, 16, 64));
        mx = fmaxf(mx, __shfl_xor(mx, 32, 64));

        // defer-max: only rescale when max grew by > 8
        if (!__all(mx <= mrun + 8.0f)) {
            float mnew = fmaxf(mrun, mx);
            float al = __expf(mrun - mnew);
            float a0 = __shfl(al, lg * 4 + 0, 64);
            float a1 = __shfl(al, lg * 4 + 1, 64);
            float a2 = __shfl(al, lg * 4 + 2, 64);
            float a3 = __shfl(al, lg * 4 + 3, 64);
#pragma unroll
            for (int dn = 0; dn < 4; dn++) {
                oacc[dn][0] *= a0; oacc[dn][1] *= a1;
                oacc[dn][2] *= a2; oacc[dn][3] *= a3;
            }
            lrun *= al;
            mrun = mnew;
        }

        float rsum = 0.f;
#pragma unroll
        for (int n = 0; n < 4; n++)
#pragma unroll
            for (int r = 0; r < 4; r++) {
                float p = __expf(sacc[n][r] - mrun);
                sacc[n][r] = p;
                rsum += p;
            }
        rsum += __shfl_xor(rsum, 16, 64);
        rsum += __shfl_xor(rsum, 32, 64);
        lrun += rsum;

        // pack P -> wave-private LDS: 2x cvt_pk + 1x b64 write per n-tile
        ushort_t* Pw = &Ps[wave][0];
#pragma unroll
        for (int n = 0; n < 4; n++) {
            unsigned w0, w1;
            asm("v_cvt_pk_bf16_f32 %0, %1, %2" : "=v"(w0) : "v"(sacc[n][0]), "v"(sacc[n][1]));
            asm("v_cvt_pk_bf16_f32 %0, %1, %2" : "=v"(w1) : "v"(sacc[n][2]), "v"(sacc[n][3]));
            int kc = n * 2 + (lg >> 1);
            uint2 u; u.x = w0; u.y = w1;
            *(uint2*)((char*)Pw + lr * 128 + ((kc ^ (lr & 7)) << 4) + (lg & 1) * 8) = u;
        }

        // O += P V  (same-wave LDS round-trip; no barrier needed)
        short8 pf0 = *(const short8*)(Pw + lr * 64 + ((lg ^ (lr & 7)) << 3));
        short8 pf1 = *(const short8*)(Pw + lr * 64 + (((4 + lg) ^ (lr & 7)) << 3));
        __builtin_amdgcn_s_setprio(1);
#pragma unroll
        for (int dn = 0; dn < 4; dn++) {
            int r = dn * 16 + lr;
            short8 v0 = *(const short8*)(Vc + r * 64 + ((lg ^ (r & 7)) << 3));
            short8 v1 = *(const short8*)(Vc + r * 64 + (((4 + lg) ^ (r & 7)) << 3));
            oacc[dn] = __builtin_amdgcn_mfma_f32_16x16x32_bf16(pf0, v0, oacc[dn], 0, 0, 0);
            oacc[dn] = __builtin_amdgcn_mfma_f32_16x16x32_bf16(pf1, v1, oacc[dn], 0, 0, 0);
        }
        __builtin_amdgcn_s_setprio(0);
        __syncthreads();   // prefetched tile landed; all waves done with cur
        cur ^= 1;
    }

    // redistribute l (held at lane q for q=lr) to accumulator rows lg*4+reg
    float linv[4];
#pragma unroll
    for (int r = 0; r < 4; r++) linv[r] = 1.0f / __shfl(lrun, lg * 4 + r, 64);

#pragma unroll
    for (int dn = 0; dn < 4; dn++)
#pragma unroll
        for (int q = 0; q < 4; q++) {
            float o = oacc[dn][q] * linv[q];
            int row = qRow0 + wave * 16 + lg * 4 + q;
            int col = hc + dn * 16 + lr;
            O[(size_t)row * 1024 + col] = f2bf(o);
        }
}

// ---------------------------------------------------------------------------
// Host-side orchestration
// ---------------------------------------------------------------------------
extern "C" void kernel_launch(void* const* d_in, const int* in_sizes, int n_in,
                              void* d_out, int out_size, void* d_ws, size_t ws_size,
                              hipStream_t stream) {
    const float* x     = (const float*)d_in[0];
    const float* ctx   = (const float*)d_in[1];
    const float* w_qkv = (const float*)d_in[2];
    const float* b_qkv = (const float*)d_in[3];
    const float* w_os  = (const float*)d_in[4];
    const float* b_os  = (const float*)d_in[5];
    const float* w_qc  = (const float*)d_in[6];
    const float* b_qc  = (const float*)d_in[7];
    const float* w_kvc = (const float*)d_in[8];
    const float* b_kvc = (const float*)d_in[9];
    const float* w_oc  = (const float*)d_in[10];
    const float* b_oc  = (const float*)d_in[11];
    const float* w_fc1 = (const float*)d_in[12];
    const float* b_fc1 = (const float*)d_in[13];
    const float* w_fc2 = (const float*)d_in[14];
    const float* b_fc2 = (const float*)d_in[15];
    float* out = (float*)d_out;

    char* ws = (char*)d_ws;
    // weight arena (bf16, transposed N x K)
    ushort_t* wqkvT = (ushort_t*)(ws + 0);          // 3072x1024
    ushort_t* wosT  = (ushort_t*)(ws + 6291456);    // 1024x1024
    ushort_t* wqcT  = (ushort_t*)(ws + 8388608);    // 1024x1024
    ushort_t* wkvcT = (ushort_t*)(ws + 10485760);   // 2048x1024
    ushort_t* wocT  = (ushort_t*)(ws + 14680064);   // 1024x1024
    ushort_t* wfc1T = (ushort_t*)(ws + 16777216);   // 4096x1024
    ushort_t* wfc2T = (ushort_t*)(ws + 25165824);   // 1024x4096
    // activation arena (liveness-overlapped)
    ushort_t* qkv_bf  = (ushort_t*)(ws + 33554432); // 8192x3072 (self phase)
    ushort_t* q_bf    = (ushort_t*)(ws + 33554432); // 8192x1024 (cross phase)
    ushort_t* kv_bf   = (ushort_t*)(ws + 50331648); // 4096x2048 (cross phase)
    ushort_t* vt_c    = (ushort_t*)(ws + 67108864); // 64*64x1024 cross V^T (cross phase)
    ushort_t* ffn_bf  = (ushort_t*)(ws + 33554432); // 8192x4096 (ffn phase)
    ushort_t* ctx_bf  = (ushort_t*)(ws + 83886080); // 4096x1024 (dead before ffn)
    ushort_t* attn_bf = (ushort_t*)(ws + 92274688); // 8192x1024 (dead before ffn)
    ushort_t* h_bf    = (ushort_t*)(ws + 109051904);// 8192x1024 (LN out; dead during attn)
    ushort_t* vt_s    = (ushort_t*)(ws + 109051904);// 64*64x2048 self V^T (aliases h_bf)

    const dim3 tb(256);
    const dim3 tb512(512);
    // weight conversion/transpose
    w_transpose_bf16<<<dim3(48, 16), tb, 0, stream>>>(w_qkv, wqkvT, 1024, 3072);
    w_transpose_bf16<<<dim3(16, 16), tb, 0, stream>>>(w_os,  wosT,  1024, 1024);
    w_transpose_bf16<<<dim3(16, 16), tb, 0, stream>>>(w_qc,  wqcT,  1024, 1024);
    w_transpose_bf16<<<dim3(32, 16), tb, 0, stream>>>(w_kvc, wkvcT, 1024, 2048);
    w_transpose_bf16<<<dim3(16, 16), tb, 0, stream>>>(w_oc,  wocT,  1024, 1024);
    w_transpose_bf16<<<dim3(64, 16), tb, 0, stream>>>(w_fc1, wfc1T, 1024, 4096);
    w_transpose_bf16<<<dim3(16, 64), tb, 0, stream>>>(w_fc2, wfc2T, 4096, 1024);
    f32_to_bf16_vec<<<4096, tb, 0, stream>>>(ctx, ctx_bf, 1048576);

    // ---- self-attention sub-block ----
    ln_rows<<<8192, tb, 0, stream>>>(x, h_bf);
    gemm256_bt<EPI_BF16><<<dim3(12, 32), tb512, 0, stream>>>(h_bf, wqkvT, b_qkv, qkv_bf, 8192, 3072, 1024);
    v_transpose<<<dim3(32, 64), tb, 0, stream>>>(qkv_bf + 2048, 3072, 2048, vt_s, 2048);
    attn_fwd<<<dim3(16, 16, 4), tb512, 0, stream>>>(qkv_bf, 3072, qkv_bf + 1024, 3072, 2048,
                                                    vt_s, 2048, attn_bf);
    gemm_bt<EPI_RES><<<dim3(8, 64), tb, 0, stream>>>(attn_bf, wosT, b_os, x, out, 8192, 1024, 1024);

    // ---- cross-attention sub-block ----
    ln_rows<<<8192, tb, 0, stream>>>(out, h_bf);
    gemm_bt<EPI_BF16><<<dim3(8, 64), tb, 0, stream>>>(h_bf, wqcT, b_qc, nullptr, q_bf, 8192, 1024, 1024);
    gemm_bt<EPI_BF16><<<dim3(16, 32), tb, 0, stream>>>(ctx_bf, wkvcT, b_kvc, nullptr, kv_bf, 4096, 2048, 1024);
    v_transpose<<<dim3(16, 64), tb, 0, stream>>>(kv_bf + 1024, 2048, 1024, vt_c, 1024);
    attn_fwd<<<dim3(16, 16, 4), tb512, 0, stream>>>(q_bf, 1024, kv_bf, 2048, 1024,
                                                    vt_c, 1024, attn_bf);
    gemm_bt<EPI_RES><<<dim3(8, 64), tb, 0, stream>>>(attn_bf, wocT, b_oc, out, out, 8192, 1024, 1024);

    // ---- FFN sub-block ----
    ln_rows<<<8192, tb, 0, stream>>>(out, h_bf);
    gemm256_bt<EPI_GELU><<<dim3(16, 32), tb512, 0, stream>>>(h_bf, wfc1T, b_fc1, ffn_bf, 8192, 4096, 1024);
    gemm_bt<EPI_RES><<<dim3(8, 64), tb, 0, stream>>>(ffn_bf, wfc2T, b_fc2, out, out, 8192, 1024, 4096);
}

// Round 5
// 589.564 us; speedup vs baseline: 1.0566x; 1.0566x over previous
//
#include <hip/hip_runtime.h>

typedef unsigned short ushort_t;
typedef __attribute__((ext_vector_type(8))) short short8;
typedef __attribute__((ext_vector_type(4))) float f32x4;
typedef __attribute__((ext_vector_type(4))) unsigned short ushort4v;

__device__ inline ushort_t f2bf(float f) {
    union { float f; unsigned u; } v; v.f = f;
    return (ushort_t)((v.u + 0x7FFFu + ((v.u >> 16) & 1u)) >> 16);
}
__device__ inline float bf2f(ushort_t u) {
    union { unsigned u; float f; } v; v.u = ((unsigned)u) << 16;
    return v.f;
}

// async global->LDS, 16B per lane. LDS dest must be wave-uniform-base + lane*16.
__device__ inline void gld16(const ushort_t* g, ushort_t* l) {
    __builtin_amdgcn_global_load_lds(
        (const __attribute__((address_space(1))) unsigned int*)g,
        (__attribute__((address_space(3))) unsigned int*)l, 16, 0, 0);
}

// XCD-aware bijective block swizzle (nwg must be a multiple of 8):
// dispatch id i lands on XCD i%8; remap so each XCD owns a contiguous work chunk.
__device__ inline int xcd_swz(int id, int nwg) {
    int q = nwg >> 3;
    return (id & 7) * q + (id >> 3);
}

// ---------------------------------------------------------------------------
// Weight transpose + f32->bf16 convert:  w (K x N) f32  ->  out (N x K) bf16
// ---------------------------------------------------------------------------
__global__ void w_transpose_bf16(const float* __restrict__ w, ushort_t* __restrict__ out,
                                 int K, int N) {
    __shared__ float t[64][65];
    const int k0 = blockIdx.y * 64, n0 = blockIdx.x * 64;
    const int tid = threadIdx.x;
#pragma unroll
    for (int i = 0; i < 16; i++) {
        int idx = tid + i * 256;
        int r = idx >> 6, c = idx & 63;
        t[r][c] = w[(size_t)(k0 + r) * N + n0 + c];
    }
    __syncthreads();
#pragma unroll
    for (int i = 0; i < 16; i++) {
        int idx = tid + i * 256;
        int nr = idx >> 6, kc = idx & 63;
        out[(size_t)(n0 + nr) * K + k0 + kc] = f2bf(t[kc][nr]);
    }
}

// ---------------------------------------------------------------------------
// bf16 V (rows x D per head, strided) -> Vt [(b*16+h)*64 + d][Lk]
// ---------------------------------------------------------------------------
__global__ void v_transpose(const ushort_t* __restrict__ V, int vStride, int rowsPerBatch,
                            ushort_t* __restrict__ Vt, int Lk) {
    __shared__ __align__(16) ushort_t t[64][72];
    const int bh = blockIdx.y, k0 = blockIdx.x * 64;
    const int b = bh >> 4, h = bh & 15;
    const int tid = threadIdx.x;
    const ushort_t* src = V + (size_t)(b * rowsPerBatch + k0) * vStride + h * 64;
#pragma unroll
    for (int i = 0; i < 2; i++) {
        int ch = tid + i * 256;
        int r = ch >> 3, c = (ch & 7) * 8;
        *(short8*)(&t[r][c]) = *(const short8*)(src + (size_t)r * vStride + c);
    }
    __syncthreads();
#pragma unroll
    for (int i = 0; i < 2; i++) {
        int ch = tid + i * 256;
        int d = ch >> 3, c = (ch & 7) * 8;
        short8 o;
#pragma unroll
        for (int j = 0; j < 8; j++) o[j] = (short)t[c + j][d];
        *(short8*)(Vt + ((size_t)bh * 64 + d) * Lk + k0 + c) = o;
    }
}

// ---------------------------------------------------------------------------
// Elementwise f32 -> bf16 (vectorized x4)
// ---------------------------------------------------------------------------
__global__ void f32_to_bf16_vec(const float* __restrict__ in, ushort_t* __restrict__ out, int n4) {
    int i = blockIdx.x * blockDim.x + threadIdx.x;
    if (i < n4) {
        float4 v = ((const float4*)in)[i];
        ushort4v o;
        o[0] = f2bf(v.x); o[1] = f2bf(v.y); o[2] = f2bf(v.z); o[3] = f2bf(v.w);
        ((ushort4v*)out)[i] = o;
    }
}

// ---------------------------------------------------------------------------
// LayerNorm over C=1024, f32 in -> bf16 out. One row per block (256 thr).
// ---------------------------------------------------------------------------
__global__ void ln_rows(const float* __restrict__ in, ushort_t* __restrict__ out) {
    __shared__ float s1[4], s2[4];
    const int row = blockIdx.x;
    const int tid = threadIdx.x;
    const float4 v = ((const float4*)(in + (size_t)row * 1024))[tid];
    float s  = v.x + v.y + v.z + v.w;
    float ss = v.x * v.x + v.y * v.y + v.z * v.z + v.w * v.w;
#pragma unroll
    for (int d = 32; d >= 1; d >>= 1) {
        s  += __shfl_down(s, d, 64);
        ss += __shfl_down(ss, d, 64);
    }
    if ((tid & 63) == 0) { s1[tid >> 6] = s; s2[tid >> 6] = ss; }
    __syncthreads();
    float sum = s1[0] + s1[1] + s1[2] + s1[3];
    float sqs = s2[0] + s2[1] + s2[2] + s2[3];
    float mu  = sum * (1.0f / 1024.0f);
    float var = sqs * (1.0f / 1024.0f) - mu * mu;
    float rs  = rsqrtf(var + 1e-6f);
    ushort4v o;
    o[0] = f2bf((v.x - mu) * rs);
    o[1] = f2bf((v.y - mu) * rs);
    o[2] = f2bf((v.z - mu) * rs);
    o[3] = f2bf((v.w - mu) * rs);
    ((ushort4v*)(out + (size_t)row * 1024))[tid] = o;
}

#define EPI_BF16 0
#define EPI_GELU 1
#define EPI_RES  2

// ---------------------------------------------------------------------------
// 128x128 bf16 MFMA GEMM (m97-structure) + XCD-aware block swizzle.
// global_load_lds(16B) staging: linear LDS dest, inverse-swizzled source col.
// ---------------------------------------------------------------------------
template <int EPI>
__global__ void gemm_bt(const ushort_t* __restrict__ A, const ushort_t* __restrict__ Bt,
                        const float* __restrict__ bias, const float* __restrict__ res,
                        void* __restrict__ outp, int M, int N, int K) {
    __shared__ __align__(16) ushort_t As[128 * 64];
    __shared__ __align__(16) ushort_t Bs[128 * 64];
    const int tid = threadIdx.x;
    const int lane = tid & 63, wave = tid >> 6;
    const int nwg = gridDim.x * gridDim.y;
    const int sid = xcd_swz(blockIdx.y * gridDim.x + blockIdx.x, nwg);
    const int m0 = (sid / gridDim.x) * 128, n0 = (sid % gridDim.x) * 128;
    const int wr = (wave >> 1) * 64, wc = (wave & 1) * 64;
    const int lr = lane & 15, lg = lane >> 4;

    f32x4 acc[4][4];
#pragma unroll
    for (int i = 0; i < 4; i++)
#pragma unroll
        for (int j = 0; j < 4; j++) acc[i][j] = f32x4{0.f, 0.f, 0.f, 0.f};

    for (int k0 = 0; k0 < K; k0 += 64) {
#pragma unroll
        for (int i = 0; i < 4; i++) {
            int ch = tid + i * 256;
            int r = ch >> 3;
            int kcs = (((ch & 7) ^ (r & 7))) * 8;
            gld16(A  + (size_t)(m0 + r) * K + k0 + kcs, As + ch * 8);
            gld16(Bt + (size_t)(n0 + r) * K + k0 + kcs, Bs + ch * 8);
        }
        __syncthreads();
#pragma unroll
        for (int ks = 0; ks < 2; ks++) {
            short8 af[4], bfr[4];
#pragma unroll
            for (int m = 0; m < 4; m++) {
                int r = wr + m * 16 + lr;
                int kc = ks * 4 + lg;
                af[m] = *(const short8*)(As + r * 64 + ((kc ^ (r & 7)) << 3));
            }
#pragma unroll
            for (int n = 0; n < 4; n++) {
                int r = wc + n * 16 + lr;
                int kc = ks * 4 + lg;
                bfr[n] = *(const short8*)(Bs + r * 64 + ((kc ^ (r & 7)) << 3));
            }
#pragma unroll
            for (int m = 0; m < 4; m++)
#pragma unroll
                for (int n = 0; n < 4; n++)
                    acc[m][n] = __builtin_amdgcn_mfma_f32_16x16x32_bf16(af[m], bfr[n], acc[m][n], 0, 0, 0);
        }
        __syncthreads();
    }

#pragma unroll
    for (int m = 0; m < 4; m++) {
        int rowb = m0 + wr + m * 16 + lg * 4;
#pragma unroll
        for (int n = 0; n < 4; n++) {
            int col = n0 + wc + n * 16 + lr;
            float bcol = bias[col];
            f32x4 v = acc[m][n];
#pragma unroll
            for (int q = 0; q < 4; q++) {
                float x = v[q] + bcol;
                if (EPI == EPI_GELU) {
                    float u = 0.7978845608028654f * (x + 0.044715f * x * x * x);
                    x = 0.5f * x * (1.0f + tanhf(u));
                }
                size_t off = (size_t)(rowb + q) * N + col;
                if (EPI == EPI_RES) ((float*)outp)[off] = x + res[off];
                else                ((ushort_t*)outp)[off] = f2bf(x);
            }
        }
    }
}

// ---------------------------------------------------------------------------
// Flash attention, bf16 MFMA 16x16x32, D=64. Block = 128 q-rows x 1 head,
// 8 waves (16 q-rows each). Swapped QK^T, packed P, defer-max, double-buffered
// K/V^T staging via global_load_lds, setprio, XCD-swizzled 1-D grid.
// Grid: 1024 blocks = 16 qb x 16 h x 4 b.
// ---------------------------------------------------------------------------
__global__ __launch_bounds__(512, 2)
void attn_fwd(const ushort_t* __restrict__ Q, int qStride,
              const ushort_t* __restrict__ Kp, int kvStride, int kvBatchRows,
              const ushort_t* __restrict__ Vt, int Lk,
              ushort_t* __restrict__ O) {
    __shared__ __align__(16) ushort_t Ks[2][64 * 64];
    __shared__ __align__(16) ushort_t Vts[2][64 * 64];
    __shared__ __align__(16) ushort_t Ps[8][16 * 64];
    const int tid = threadIdx.x, lane = tid & 63, wave = tid >> 6;
    const int lr = lane & 15, lg = lane >> 4;
    const int sid = xcd_swz(blockIdx.x, gridDim.x);
    const int qb = sid & 15, h = (sid >> 4) & 15, b = sid >> 8;
    const int qRow0 = b * 2048 + qb * 128;
    const int kvRow0 = b * kvBatchRows;
    const int hc = h * 64;
    const ushort_t* vt_base = Vt + (size_t)(b * 16 + h) * 64 * Lk;

    // Q fragments, pre-scaled by 1/sqrt(64)=0.125 (exact in bf16)
    short8 qf[2];
    {
        const ushort_t* qrow = Q + (size_t)(qRow0 + wave * 16 + lr) * qStride + hc;
        short8 r0 = *(const short8*)(qrow + lg * 8);
        short8 r1 = *(const short8*)(qrow + 32 + lg * 8);
#pragma unroll
        for (int j = 0; j < 8; j++) {
            qf[0][j] = (short)f2bf(bf2f((ushort_t)r0[j]) * 0.125f);
            qf[1][j] = (short)f2bf(bf2f((ushort_t)r1[j]) * 0.125f);
        }
    }

    f32x4 oacc[4];
#pragma unroll
    for (int d = 0; d < 4; d++) oacc[d] = f32x4{0.f, 0.f, 0.f, 0.f};
    float mrun = -INFINITY, lrun = 0.f;

    const int nt = Lk >> 6;

    auto stage = [&](int buf, int kt) {
        int r = tid >> 3;
        int kcs = (((tid & 7) ^ (r & 7))) * 8;
        gld16(Kp + (size_t)(kvRow0 + kt + r) * kvStride + hc + kcs, Ks[buf] + tid * 8);
        gld16(vt_base + (size_t)r * Lk + kt + kcs, Vts[buf] + tid * 8);
    };

    stage(0, 0);
    __syncthreads();
    int cur = 0;

    for (int t = 0; t < nt; ++t) {
        if (t + 1 < nt) stage(cur ^ 1, (t + 1) * 64);

        const ushort_t* Kc = Ks[cur];
        const ushort_t* Vc = Vts[cur];

        // S^T = K Q^T : lane holds S[q=lr][k = n*16 + lg*4 + reg]
        f32x4 sacc[4];
        __builtin_amdgcn_s_setprio(1);
#pragma unroll
        for (int n = 0; n < 4; n++) {
            int r = n * 16 + lr;
            short8 k0 = *(const short8*)(Kc + r * 64 + ((lg ^ (r & 7)) << 3));
            short8 k1 = *(const short8*)(Kc + r * 64 + (((4 + lg) ^ (r & 7)) << 3));
            f32x4 s = f32x4{0.f, 0.f, 0.f, 0.f};
            s = __builtin_amdgcn_mfma_f32_16x16x32_bf16(k0, qf[0], s, 0, 0, 0);
            s = __builtin_amdgcn_mfma_f32_16x16x32_bf16(k1, qf[1], s, 0, 0, 0);
            sacc[n] = s;
        }
        __builtin_amdgcn_s_setprio(0);

        // row max: 15 in-reg fmax + 2 cross-lane
        float mx = sacc[0][0];
#pragma unroll
        for (int n = 0; n < 4; n++)
#pragma unroll
            for (int r = 0; r < 4; r++) if (n | r) mx = fmaxf(mx, sacc[n][r]);
        mx = fmaxf(mx, __shfl_xor(mx, 16, 64));
        mx = fmaxf(mx, __shfl_xor(mx, 32, 64));

        // defer-max: only rescale when max grew by > 8
        if (!__all(mx <= mrun + 8.0f)) {
            float mnew = fmaxf(mrun, mx);
            float al = __expf(mrun - mnew);
            float a0 = __shfl(al, lg * 4 + 0, 64);
            float a1 = __shfl(al, lg * 4 + 1, 64);
            float a2 = __shfl(al, lg * 4 + 2, 64);
            float a3 = __shfl(al, lg * 4 + 3, 64);
#pragma unroll
            for (int dn = 0; dn < 4; dn++) {
                oacc[dn][0] *= a0; oacc[dn][1] *= a1;
                oacc[dn][2] *= a2; oacc[dn][3] *= a3;
            }
            lrun *= al;
            mrun = mnew;
        }

        float rsum = 0.f;
#pragma unroll
        for (int n = 0; n < 4; n++)
#pragma unroll
            for (int r = 0; r < 4; r++) {
                float p = __expf(sacc[n][r] - mrun);
                sacc[n][r] = p;
                rsum += p;
            }
        rsum += __shfl_xor(rsum, 16, 64);
        rsum += __shfl_xor(rsum, 32, 64);
        lrun += rsum;

        // pack P -> wave-private LDS: 2x cvt_pk + 1x b64 write per n-tile
        ushort_t* Pw = &Ps[wave][0];
#pragma unroll
        for (int n = 0; n < 4; n++) {
            unsigned w0, w1;
            asm("v_cvt_pk_bf16_f32 %0, %1, %2" : "=v"(w0) : "v"(sacc[n][0]), "v"(sacc[n][1]));
            asm("v_cvt_pk_bf16_f32 %0, %1, %2" : "=v"(w1) : "v"(sacc[n][2]), "v"(sacc[n][3]));
            int kc = n * 2 + (lg >> 1);
            uint2 u; u.x = w0; u.y = w1;
            *(uint2*)((char*)Pw + lr * 128 + ((kc ^ (lr & 7)) << 4) + (lg & 1) * 8) = u;
        }

        // O += P V  (same-wave LDS round-trip; no barrier needed)
        short8 pf0 = *(const short8*)(Pw + lr * 64 + ((lg ^ (lr & 7)) << 3));
        short8 pf1 = *(const short8*)(Pw + lr * 64 + (((4 + lg) ^ (lr & 7)) << 3));
        __builtin_amdgcn_s_setprio(1);
#pragma unroll
        for (int dn = 0; dn < 4; dn++) {
            int r = dn * 16 + lr;
            short8 v0 = *(const short8*)(Vc + r * 64 + ((lg ^ (r & 7)) << 3));
            short8 v1 = *(const short8*)(Vc + r * 64 + (((4 + lg) ^ (r & 7)) << 3));
            oacc[dn] = __builtin_amdgcn_mfma_f32_16x16x32_bf16(pf0, v0, oacc[dn], 0, 0, 0);
            oacc[dn] = __builtin_amdgcn_mfma_f32_16x16x32_bf16(pf1, v1, oacc[dn], 0, 0, 0);
        }
        __builtin_amdgcn_s_setprio(0);
        __syncthreads();   // prefetched tile landed; all waves done with cur
        cur ^= 1;
    }

    // redistribute l (held at lane q for q=lr) to accumulator rows lg*4+reg
    float linv[4];
#pragma unroll
    for (int r = 0; r < 4; r++) linv[r] = 1.0f / __shfl(lrun, lg * 4 + r, 64);

#pragma unroll
    for (int dn = 0; dn < 4; dn++)
#pragma unroll
        for (int q = 0; q < 4; q++) {
            float o = oacc[dn][q] * linv[q];
            int row = qRow0 + wave * 16 + lg * 4 + q;
            int col = hc + dn * 16 + lr;
            O[(size_t)row * 1024 + col] = f2bf(o);
        }
}

// ---------------------------------------------------------------------------
// Host-side orchestration
// ---------------------------------------------------------------------------
extern "C" void kernel_launch(void* const* d_in, const int* in_sizes, int n_in,
                              void* d_out, int out_size, void* d_ws, size_t ws_size,
                              hipStream_t stream) {
    const float* x     = (const float*)d_in[0];
    const float* ctx   = (const float*)d_in[1];
    const float* w_qkv = (const float*)d_in[2];
    const float* b_qkv = (const float*)d_in[3];
    const float* w_os  = (const float*)d_in[4];
    const float* b_os  = (const float*)d_in[5];
    const float* w_qc  = (const float*)d_in[6];
    const float* b_qc  = (const float*)d_in[7];
    const float* w_kvc = (const float*)d_in[8];
    const float* b_kvc = (const float*)d_in[9];
    const float* w_oc  = (const float*)d_in[10];
    const float* b_oc  = (const float*)d_in[11];
    const float* w_fc1 = (const float*)d_in[12];
    const float* b_fc1 = (const float*)d_in[13];
    const float* w_fc2 = (const float*)d_in[14];
    const float* b_fc2 = (const float*)d_in[15];
    float* out = (float*)d_out;

    char* ws = (char*)d_ws;
    // weight arena (bf16, transposed N x K)
    ushort_t* wqkvT = (ushort_t*)(ws + 0);          // 3072x1024
    ushort_t* wosT  = (ushort_t*)(ws + 6291456);    // 1024x1024
    ushort_t* wqcT  = (ushort_t*)(ws + 8388608);    // 1024x1024
    ushort_t* wkvcT = (ushort_t*)(ws + 10485760);   // 2048x1024
    ushort_t* wocT  = (ushort_t*)(ws + 14680064);   // 1024x1024
    ushort_t* wfc1T = (ushort_t*)(ws + 16777216);   // 4096x1024
    ushort_t* wfc2T = (ushort_t*)(ws + 25165824);   // 1024x4096
    // activation arena (liveness-overlapped)
    ushort_t* qkv_bf  = (ushort_t*)(ws + 33554432); // 8192x3072 (self phase)
    ushort_t* q_bf    = (ushort_t*)(ws + 33554432); // 8192x1024 (cross phase)
    ushort_t* kv_bf   = (ushort_t*)(ws + 50331648); // 4096x2048 (cross phase)
    ushort_t* vt_c    = (ushort_t*)(ws + 67108864); // 64*64x1024 cross V^T (cross phase)
    ushort_t* ffn_bf  = (ushort_t*)(ws + 33554432); // 8192x4096 (ffn phase)
    ushort_t* ctx_bf  = (ushort_t*)(ws + 83886080); // 4096x1024 (dead before ffn)
    ushort_t* attn_bf = (ushort_t*)(ws + 92274688); // 8192x1024 (dead before ffn)
    ushort_t* h_bf    = (ushort_t*)(ws + 109051904);// 8192x1024 (LN out; dead during attn)
    ushort_t* vt_s    = (ushort_t*)(ws + 109051904);// 64*64x2048 self V^T (aliases h_bf)

    const dim3 tb(256);
    const dim3 tb512(512);
    // weight conversion/transpose
    w_transpose_bf16<<<dim3(48, 16), tb, 0, stream>>>(w_qkv, wqkvT, 1024, 3072);
    w_transpose_bf16<<<dim3(16, 16), tb, 0, stream>>>(w_os,  wosT,  1024, 1024);
    w_transpose_bf16<<<dim3(16, 16), tb, 0, stream>>>(w_qc,  wqcT,  1024, 1024);
    w_transpose_bf16<<<dim3(32, 16), tb, 0, stream>>>(w_kvc, wkvcT, 1024, 2048);
    w_transpose_bf16<<<dim3(16, 16), tb, 0, stream>>>(w_oc,  wocT,  1024, 1024);
    w_transpose_bf16<<<dim3(64, 16), tb, 0, stream>>>(w_fc1, wfc1T, 1024, 4096);
    w_transpose_bf16<<<dim3(16, 64), tb, 0, stream>>>(w_fc2, wfc2T, 4096, 1024);
    f32_to_bf16_vec<<<4096, tb, 0, stream>>>(ctx, ctx_bf, 1048576);

    // ---- self-attention sub-block ----
    ln_rows<<<8192, tb, 0, stream>>>(x, h_bf);
    gemm_bt<EPI_BF16><<<dim3(24, 64), tb, 0, stream>>>(h_bf, wqkvT, b_qkv, nullptr, qkv_bf, 8192, 3072, 1024);
    v_transpose<<<dim3(32, 64), tb, 0, stream>>>(qkv_bf + 2048, 3072, 2048, vt_s, 2048);
    attn_fwd<<<dim3(1024), tb512, 0, stream>>>(qkv_bf, 3072, qkv_bf + 1024, 3072, 2048,
                                               vt_s, 2048, attn_bf);
    gemm_bt<EPI_RES><<<dim3(8, 64), tb, 0, stream>>>(attn_bf, wosT, b_os, x, out, 8192, 1024, 1024);

    // ---- cross-attention sub-block ----
    ln_rows<<<8192, tb, 0, stream>>>(out, h_bf);
    gemm_bt<EPI_BF16><<<dim3(8, 64), tb, 0, stream>>>(h_bf, wqcT, b_qc, nullptr, q_bf, 8192, 1024, 1024);
    gemm_bt<EPI_BF16><<<dim3(16, 32), tb, 0, stream>>>(ctx_bf, wkvcT, b_kvc, nullptr, kv_bf, 4096, 2048, 1024);
    v_transpose<<<dim3(16, 64), tb, 0, stream>>>(kv_bf + 1024, 2048, 1024, vt_c, 1024);
    attn_fwd<<<dim3(1024), tb512, 0, stream>>>(q_bf, 1024, kv_bf, 2048, 1024,
                                               vt_c, 1024, attn_bf);
    gemm_bt<EPI_RES><<<dim3(8, 64), tb, 0, stream>>>(attn_bf, wocT, b_oc, out, out, 8192, 1024, 1024);

    // ---- FFN sub-block ----
    ln_rows<<<8192, tb, 0, stream>>>(out, h_bf);
    gemm_bt<EPI_GELU><<<dim3(32, 64), tb, 0, stream>>>(h_bf, wfc1T, b_fc1, nullptr, ffn_bf, 8192, 4096, 1024);
    gemm_bt<EPI_RES><<<dim3(8, 64), tb, 0, stream>>>(ffn_bf, wfc2T, b_fc2, out, out, 8192, 1024, 4096);
}